// Round 9
// baseline (47609.775 us; speedup 1.0000x reference)
//
#include <hip/hip_runtime.h>
#include <hip/hip_fp16.h>

#define N 4096
#define L 4096
#define NPART 32     // i-chunks (rows 128 each)
#define NJB 16       // j-blocks (cols 256 each)
#define CPB 256      // cols per block
#define RPB 128      // rows per block
#define LROWS 112    // rows of the tile staged in LDS (56 KiB); rows 112-127 via global

#define AS(p, v) __hip_atomic_store((p), (v), __ATOMIC_RELAXED, __HIP_MEMORY_SCOPE_AGENT)
#define AL(p)    __hip_atomic_load((p), __ATOMIC_RELAXED, __HIP_MEMORY_SCOPE_AGENT)

typedef __attribute__((address_space(1))) const unsigned int gv_t;
typedef __attribute__((address_space(3))) unsigned int lv_t;

// ---------- init: zero d_out, seed triple partial buffer, zero ready counters ----------
__global__ __launch_bounds__(256) void init_kernel(const float* __restrict__ sd,
                                                   float* __restrict__ vwpart,
                                                   unsigned* __restrict__ ready,
                                                   float* __restrict__ out) {
    int g = blockIdx.x * 256 + threadIdx.x;          // grid 1536 -> 393216 threads
    if (g < L * 4) out[g] = 0.0f;
    if (g < 3 * NPART * N) AS(&vwpart[g], (g < N) ? sd[g] : 0.0f);  // buf0 part0 = sd
    if (g < NJB * 64) AS(&ready[g], 0u);
}

// ---------- robust symbol decode: handles int32 OR int64 device layout ----------
__global__ __launch_bounds__(256) void decode_seq_kernel(const int* __restrict__ seq32,
                                                         unsigned char* __restrict__ syms) {
    __shared__ int any_odd;
    if (threadIdx.x == 0) any_odd = 0;
    __syncthreads();
    int acc = 0;
    for (int i = threadIdx.x; i < L / 2; i += 256) acc |= seq32[2 * i + 1];
    if (acc) any_odd = 1;
    __syncthreads();
    const int is64 = (any_odd == 0);
    for (int t = threadIdx.x; t < L; t += 256) {
        int v = is64 ? seq32[2 * t] : seq32[t];
        syms[t] = (unsigned char)(v & 1);
    }
}

// ---------- softmax over T rows -> fp16 Tm[s][i][j] + row-mass correction ----------
__global__ __launch_bounds__(256) void softmax_T_kernel(const float* __restrict__ T,
                                                        unsigned short* __restrict__ Tm,
                                                        float* __restrict__ rowc) {
    int row = blockIdx.x;              // 0..8191 == i*2 + s
    int i = row >> 1, s = row & 1;
    const float* src = T + (size_t)row * N;
    unsigned short* dst = Tm + ((size_t)s << 24) + ((size_t)i << 12);
    int tid = threadIdx.x;

    float vals[16];
    float mx = -1e30f;
#pragma unroll
    for (int k = 0; k < 16; k++) {
        vals[k] = src[tid + (k << 8)];
        mx = fmaxf(mx, vals[k]);
    }
#pragma unroll
    for (int o = 32; o > 0; o >>= 1) mx = fmaxf(mx, __shfl_xor(mx, o));
    __shared__ float red[4];
    int wid = tid >> 6;
    if ((tid & 63) == 0) red[wid] = mx;
    __syncthreads();
    mx = fmaxf(fmaxf(red[0], red[1]), fmaxf(red[2], red[3]));
    __syncthreads();

    float sum = 0.0f;
#pragma unroll
    for (int k = 0; k < 16; k++) {
        vals[k] = __expf(vals[k] - mx);
        sum += vals[k];
    }
#pragma unroll
    for (int o = 32; o > 0; o >>= 1) sum += __shfl_xor(sum, o);
    if ((tid & 63) == 0) red[wid] = sum;
    __syncthreads();
    sum = red[0] + red[1] + red[2] + red[3];
    __syncthreads();
    float inv = 1.0f / sum;

    float qs = 0.0f;
#pragma unroll
    for (int k = 0; k < 16; k++) {
        __half h = __float2half_rn(vals[k] * inv);
        dst[tid + (k << 8)] = __half_as_ushort(h);
        qs += __half2float(h);
    }
#pragma unroll
    for (int o = 32; o > 0; o >>= 1) qs += __shfl_xor(qs, o);
    if ((tid & 63) == 0) red[wid] = qs;
    __syncthreads();
    if (tid == 0) {
        float q = red[0] + red[1] + red[2] + red[3];
        rowc[(size_t)s * N + i] = 1.0f / q;
    }
}

// ---------- softmax over O rows (4 wide) -> fp32 Om[s][i][c] ----------
__global__ __launch_bounds__(256) void softmax_O_kernel(const float* __restrict__ O,
                                                        float* __restrict__ Om) {
    int r = blockIdx.x * 256 + threadIdx.x;        // 0..8191 == i*2 + s
    if (r < 2 * N) {
        float4 x = *(const float4*)(O + (size_t)r * 4);
        float mx = fmaxf(fmaxf(x.x, x.y), fmaxf(x.z, x.w));
        float e0 = __expf(x.x - mx), e1 = __expf(x.y - mx);
        float e2 = __expf(x.z - mx), e3 = __expf(x.w - mx);
        float inv = 1.0f / (e0 + e1 + e2 + e3);
        int i = r >> 1, s = r & 1;
        *(float4*)(Om + (size_t)s * (N * 4) + (size_t)i * 4) =
            make_float4(e0 * inv, e1 * inv, e2 * inv, e3 * inv);
    }
}

// ---------- persistent scan kernel: p2p sync + async LDS tile prefetch ----------
// REGULAR launch (not cooperative): 512 persistent blocks on 256 CUs (2/CU by
// LDS: 2 x 59 KiB < 160 KiB pool; 8 waves/CU at <=128 VGPR). No grid.sync —
// only p2p monotone counters, so co-residency (which the HW dispatcher gives
// us since no block ever retires) is the only requirement.
// Rows 0-111 of the step's 128x256 Tm tile are DMA'd into a 56 KiB LDS buffer
// (global_load_lds x16B) right after the step-t bump, overlapping the sync
// window; rows 112-127 (rg==7 threads) are read via global post-sync.
__global__ __launch_bounds__(256, 2) void scan_kernel(const unsigned short* __restrict__ Tm,
                                                      const float* __restrict__ rowc,
                                                      const float* __restrict__ Om,
                                                      const unsigned char* __restrict__ syms,
                                                      float* __restrict__ vwpart,
                                                      unsigned* __restrict__ ready,
                                                      float* __restrict__ out) {
    const int tid = threadIdx.x;
    const int jb = blockIdx.x & 15;
    const int ic = blockIdx.x >> 4;      // 0..31
    const int i0 = ic * RPB;
    const int j0 = jb * CPB;

    __shared__ __align__(16) unsigned short tile[LROWS * CPB];  // 56 KiB
    __shared__ float psum[2][RPB];
    __shared__ float v[RPB];      // raw state rows
    __shared__ float vc[RPB];     // row-mass-corrected state rows
    __shared__ float colacc[CPB];
    __shared__ float oacc[4];

    const int cg = tid & 31;             // col group: 8 cols each
    const int rg = tid >> 5;             // row group: 8 groups x 16 rows
    const int row = tid & 127;           // staging row
    const int half = tid >> 7;           // staging partial-half
    const int wv = tid >> 6;             // wave 0..3
    const int ln = tid & 63;             // lane

    unsigned* wait_ctr = &ready[(ic >> 1) * 64];
    unsigned* bump_ctr = &ready[jb * 64];

    // DMA rows 0..111 (56 chunks of 1 KiB = 2 tile rows each): 4 waves x 14.
    const char* tm_base = (const char*)Tm + (size_t)i0 * (N * 2) + (size_t)j0 * 2;
    auto issue_dma = [&](int s) {
        const char* gb = tm_base + ((size_t)s << 25);
#pragma unroll
        for (int k = 0; k < 14; k++) {
            int o = ((wv * 14 + k) << 10) + (ln << 4);   // byte offset in tile
            int r = o >> 9, cb = o & 511;                // tile row, col byte
            __builtin_amdgcn_global_load_lds(
                (gv_t*)(gb + (size_t)r * (N * 2) + cb),
                (lv_t*)((char*)tile + o), 16, 0, 0);
        }
    };

    issue_dma(syms[0]);

    for (int t = 0; t < L; t++) {
        const int s = syms[t];
        const float* vin  = vwpart + (size_t)(t % 3) * (NPART * N);
        float*       vout = vwpart + (size_t)((t + 1) % 3) * (NPART * N);

        float rc = (tid < RPB) ? rowc[(size_t)s * N + i0 + tid] : 0.0f;

        // ---- wait for this step's input partials (monotone counter) ----
        if (tid == 0) {
            unsigned target = 32u * (unsigned)t;
            while (AL(wait_ctr) < target) __builtin_amdgcn_s_sleep(1);
        }
        __syncthreads();   // also drains the tile DMA (vmcnt(0) per wave)

        // ---- parallel staging: 16 independent partial loads per thread ----
        {
            const float* pbase = vin + (size_t)(half * 16) * N + i0 + row;
            float accv = 0.0f;
#pragma unroll
            for (int p = 0; p < 16; p++) accv += AL(&pbase[(size_t)p * N]);
            psum[half][row] = accv;
        }
        colacc[tid] = 0.0f;
        if (tid < 4) oacc[tid] = 0.0f;
        __syncthreads();
        if (tid < RPB) {
            float a = psum[0][tid] + psum[1][tid];
            v[tid] = a;
            vc[tid] = a * rc;
        }
        __syncthreads();

        // ---- FMA phase: rows [rg*16,+16), cols [cg*8,+8) ----
        float a[8];
#pragma unroll
        for (int e = 0; e < 8; e++) a[e] = 0.0f;

        if (rg < 7) {
            // LDS tile path (rows 0..111)
#pragma unroll
            for (int r = 0; r < 16; r++) {
                float vi = vc[rg * 16 + r];
                uint4 w = *(const uint4*)&tile[((rg * 16 + r) << 8) + (cg << 3)];
                float2 f0 = __half22float2(*(__half2*)&w.x);
                float2 f1 = __half22float2(*(__half2*)&w.y);
                float2 f2 = __half22float2(*(__half2*)&w.z);
                float2 f3 = __half22float2(*(__half2*)&w.w);
                a[0] += vi * f0.x; a[1] += vi * f0.y;
                a[2] += vi * f1.x; a[3] += vi * f1.y;
                a[4] += vi * f2.x; a[5] += vi * f2.y;
                a[6] += vi * f3.x; a[7] += vi * f3.y;
            }
        } else {
            // global path (rows 112..127), preload all 16 rows into registers
            const char* gb = tm_base + ((size_t)s << 25)
                           + (size_t)LROWS * (N * 2) + (cg << 4);
            uint4 w[16];
#pragma unroll
            for (int r = 0; r < 16; r++)
                w[r] = *(const uint4*)(gb + (size_t)r * (N * 2));
#pragma unroll
            for (int r = 0; r < 16; r++) {
                float vi = vc[LROWS + r];
                float2 f0 = __half22float2(*(__half2*)&w[r].x);
                float2 f1 = __half22float2(*(__half2*)&w[r].y);
                float2 f2 = __half22float2(*(__half2*)&w[r].z);
                float2 f3 = __half22float2(*(__half2*)&w[r].w);
                a[0] += vi * f0.x; a[1] += vi * f0.y;
                a[2] += vi * f1.x; a[3] += vi * f1.y;
                a[4] += vi * f2.x; a[5] += vi * f2.y;
                a[6] += vi * f3.x; a[7] += vi * f3.y;
            }
        }
#pragma unroll
        for (int e = 0; e < 8; e++) atomicAdd(&colacc[cg * 8 + e], a[e]);

        // ---- fused output projection partials (jb==0 blocks) — RAW state v ----
        if (jb == 0) {
            int r = tid >> 2, c = tid & 3;   // r in [0,64)
            float p = v[r] * Om[((size_t)s * N + (i0 + r)) * 4 + c]
                    + v[r + 64] * Om[((size_t)s * N + (i0 + r + 64)) * 4 + c];
            p += __shfl_down(p, 32);
            p += __shfl_down(p, 16);
            p += __shfl_down(p, 8);
            p += __shfl_down(p, 4);
            if ((tid & 63) < 4) atomicAdd(&oacc[c], p);
        }
        __syncthreads();   // all tile reads + colacc done

        // ---- publish this block's exclusive partial slice (agent-scope) ----
        AS(&vout[(size_t)ic * N + j0 + tid], colacc[tid]);
        if (jb == 0 && tid < 4) atomicAdd(&out[t * 4 + tid], oacc[tid]);
        __syncthreads();   // drains vmcnt(0) -> slice visible at MALL

        if (tid == 0) {
            __hip_atomic_fetch_add(bump_ctr, 1u, __ATOMIC_RELAXED,
                                   __HIP_MEMORY_SCOPE_AGENT);
        }

        // ---- prefetch next tile; overlaps peers' publish + our next spin ----
        if (t + 1 < L) issue_dma(syms[t + 1]);
    }
}

extern "C" void kernel_launch(void* const* d_in, const int* in_sizes, int n_in,
                              void* d_out, int out_size, void* d_ws, size_t ws_size,
                              hipStream_t stream) {
    const float* sd  = (const float*)d_in[0];   // [4096]
    const int*   seq = (const int*)d_in[1];     // [4096]
    const float* T   = (const float*)d_in[2];   // [4096,2,4096]
    const float* O   = (const float*)d_in[3];   // [4096,2,4]
    float* out = (float*)d_out;                 // [4096,4]

    const size_t TM_BYTES  = (size_t)2 * N * N * 2;          // 64 MiB fp16
    const size_t RC_BYTES  = (size_t)2 * N * 4;              // 32 KiB
    const size_t OM_BYTES  = 2 * N * 4 * sizeof(float);      // 128 KiB
    const size_t VW_BYTES  = (size_t)3 * NPART * N * 4;      // 1.5 MiB
    const size_t RD_BYTES  = (size_t)NJB * 64 * 4;           // 4 KiB padded counters

    char* ws = (char*)d_ws;
    unsigned short* Tm = (unsigned short*)ws;
    float* rowc   = (float*)(ws + TM_BYTES);
    float* Om     = (float*)(ws + TM_BYTES + RC_BYTES);
    float* vwpart = (float*)(ws + TM_BYTES + RC_BYTES + OM_BYTES);
    unsigned* ready = (unsigned*)(ws + TM_BYTES + RC_BYTES + OM_BYTES + VW_BYTES);
    unsigned char* syms = (unsigned char*)(ws + TM_BYTES + RC_BYTES + OM_BYTES + VW_BYTES + RD_BYTES);

    hipLaunchKernelGGL(init_kernel, dim3(1536), dim3(256), 0, stream, sd, vwpart, ready, out);
    hipLaunchKernelGGL(decode_seq_kernel, dim3(1), dim3(256), 0, stream, seq, syms);
    hipLaunchKernelGGL(softmax_T_kernel, dim3(2 * N), dim3(256), 0, stream, T, Tm, rowc);
    hipLaunchKernelGGL(softmax_O_kernel, dim3(32), dim3(256), 0, stream, O, Om);

    // Regular (non-cooperative) launch: 512 persistent blocks, no grid.sync
    // inside — cooperative validation rejects large-LDS kernels at this grid.
    hipLaunchKernelGGL(scan_kernel, dim3(NJB * NPART), dim3(256), 0, stream,
                       Tm, rowc, Om, syms, vwpart, ready, out);
}

// Round 10
// 23714.168 us; speedup vs baseline: 2.0077x; 2.0077x over previous
//
#include <hip/hip_runtime.h>
#include <hip/hip_fp16.h>

#define N 4096
#define L 4096
#define NPART 32   // i-chunks (rows 128 each)
#define NJB 16     // j-blocks (cols 256 each)
#define CPB 256    // cols per block
#define RPB 128    // rows per block

#define AS(p, v) __hip_atomic_store((p), (v), __ATOMIC_RELAXED, __HIP_MEMORY_SCOPE_AGENT)
#define AL(p)    __hip_atomic_load((p), __ATOMIC_RELAXED, __HIP_MEMORY_SCOPE_AGENT)

typedef _Float16 f16x8 __attribute__((ext_vector_type(8)));
typedef float f32x4 __attribute__((ext_vector_type(4)));

// ---------- init: zero d_out, seed triple partial buffer, zero ready counters ----------
__global__ __launch_bounds__(256) void init_kernel(const float* __restrict__ sd,
                                                   float* __restrict__ vwpart,
                                                   unsigned* __restrict__ ready,
                                                   float* __restrict__ out) {
    int g = blockIdx.x * 256 + threadIdx.x;          // grid 1536 -> 393216 threads
    if (g < L * 4) out[g] = 0.0f;
    if (g < 3 * NPART * N) AS(&vwpart[g], (g < N) ? sd[g] : 0.0f);  // buf0 part0 = sd
    if (g < NJB * 64) AS(&ready[g], 0u);
}

// ---------- descriptor build: robust int32/int64 decode; pair or direct mode ----------
__global__ __launch_bounds__(256) void build_desc_kernel(const int* __restrict__ seq32,
                                                         unsigned char* __restrict__ midx,
                                                         int pairmode) {
    __shared__ int any_odd;
    if (threadIdx.x == 0) any_odd = 0;
    __syncthreads();
    int acc = 0;
    for (int i = threadIdx.x; i < L / 2; i += 256) acc |= seq32[2 * i + 1];
    if (acc) any_odd = 1;
    __syncthreads();
    const int is64 = (any_odd == 0);
    if (pairmode) {
        for (int k = threadIdx.x; k < L / 2; k += 256) {
            int s0 = (is64 ? seq32[4 * k]     : seq32[2 * k])     & 1;
            int s1 = (is64 ? seq32[4 * k + 2] : seq32[2 * k + 1]) & 1;
            midx[k] = (unsigned char)(s0 * 2 + s1);
        }
    } else {
        for (int t = threadIdx.x; t < L; t += 256) {
            int v = is64 ? seq32[2 * t] : seq32[t];
            midx[t] = (unsigned char)(v & 1);
        }
    }
}

// ---------- softmax over T rows -> fp16 Tm[s][i][j] + row-mass correction ----------
__global__ __launch_bounds__(256) void softmax_T_kernel(const float* __restrict__ T,
                                                        unsigned short* __restrict__ Tm,
                                                        float* __restrict__ rowc) {
    int row = blockIdx.x;              // 0..8191 == i*2 + s
    int i = row >> 1, s = row & 1;
    const float* src = T + (size_t)row * N;
    unsigned short* dst = Tm + ((size_t)s << 24) + ((size_t)i << 12);
    int tid = threadIdx.x;

    float vals[16];
    float mx = -1e30f;
#pragma unroll
    for (int k = 0; k < 16; k++) {
        vals[k] = src[tid + (k << 8)];
        mx = fmaxf(mx, vals[k]);
    }
#pragma unroll
    for (int o = 32; o > 0; o >>= 1) mx = fmaxf(mx, __shfl_xor(mx, o));
    __shared__ float red[4];
    int wid = tid >> 6;
    if ((tid & 63) == 0) red[wid] = mx;
    __syncthreads();
    mx = fmaxf(fmaxf(red[0], red[1]), fmaxf(red[2], red[3]));
    __syncthreads();

    float sum = 0.0f;
#pragma unroll
    for (int k = 0; k < 16; k++) {
        vals[k] = __expf(vals[k] - mx);
        sum += vals[k];
    }
#pragma unroll
    for (int o = 32; o > 0; o >>= 1) sum += __shfl_xor(sum, o);
    if ((tid & 63) == 0) red[wid] = sum;
    __syncthreads();
    sum = red[0] + red[1] + red[2] + red[3];
    __syncthreads();
    float inv = 1.0f / sum;

    float qs = 0.0f;
#pragma unroll
    for (int k = 0; k < 16; k++) {
        __half h = __float2half_rn(vals[k] * inv);
        dst[tid + (k << 8)] = __half_as_ushort(h);
        qs += __half2float(h);
    }
#pragma unroll
    for (int o = 32; o > 0; o >>= 1) qs += __shfl_xor(qs, o);
    if ((tid & 63) == 0) red[wid] = qs;
    __syncthreads();
    if (tid == 0) {
        float q = red[0] + red[1] + red[2] + red[3];
        rowc[(size_t)s * N + i] = 1.0f / q;
    }
}

// ---------- softmax over O rows (4 wide) -> fp32 OW[s][i][c], s in {0,1} ----------
__global__ __launch_bounds__(256) void softmax_O_kernel(const float* __restrict__ O,
                                                        float* __restrict__ OW) {
    int r = blockIdx.x * 256 + threadIdx.x;        // 0..8191 == i*2 + s
    if (r < 2 * N) {
        float4 x = *(const float4*)(O + (size_t)r * 4);
        float mx = fmaxf(fmaxf(x.x, x.y), fmaxf(x.z, x.w));
        float e0 = __expf(x.x - mx), e1 = __expf(x.y - mx);
        float e2 = __expf(x.z - mx), e3 = __expf(x.w - mx);
        float inv = 1.0f / (e0 + e1 + e2 + e3);
        int i = r >> 1, s = r & 1;
        *(float4*)(OW + (size_t)s * (N * 4) + (size_t)i * 4) =
            make_float4(e0 * inv, e1 * inv, e2 * inv, e3 * inv);
    }
}

// ---------- MFMA pair GEMM: P[ab] = Tm_a (NxN fp16) x Tm_b, fp16 out ----------
// 4096 blocks: pair = bid>>10, 128x128 C-tile per block, 4 waves x (64x64).
// Layouts (verified m89/m91/m120): A[m=lane&15][k=quad*8+j]; B[k=quad*8+j][n=lane&15];
// D row=quad*4+reg, col=lane&15.
__global__ __launch_bounds__(256) void pair_gemm_kernel(const unsigned short* __restrict__ Tm,
                                                        unsigned short* __restrict__ P) {
    int bid = blockIdx.x;
    int pair = bid >> 10;
    int tile = bid & 1023;
    int i0 = (tile >> 5) << 7;
    int j0 = (tile & 31) << 7;
    const unsigned short* A = Tm + (size_t)(pair >> 1) * ((size_t)N * N);
    const unsigned short* B = Tm + (size_t)(pair & 1) * ((size_t)N * N);
    unsigned short* Pm = P + (size_t)pair * ((size_t)N * N);

    __shared__ _Float16 Asd[128][40];         // A tile, 80B rows (b128-aligned)
    __shared__ unsigned int Btw[128][20];     // B transposed, u32 = (k even, k odd)

    const int tid = threadIdx.x;
    const int w = tid >> 6, ln = tid & 63;
    const int wrow = (w >> 1) << 6, wcol = (w & 1) << 6;
    const int q = ln >> 4, l15 = ln & 15;

    const int ar = tid >> 1, ah = tid & 1;       // A staging: row, k-half
    const int bk2 = tid & 15, bng = tid >> 4;    // B staging: k-pair, n-group

    f32x4 acc[4][4] = {};

    for (int k0 = 0; k0 < N; k0 += 32) {
        // stage A: Asd[ar][ah*16 .. +15]
        const uint4* ga = (const uint4*)(A + (size_t)(i0 + ar) * N + k0 + ah * 16);
        uint4 a0 = ga[0], a1 = ga[1];
        *(uint4*)&Asd[ar][ah * 16] = a0;
        *(uint4*)&Asd[ar][ah * 16 + 8] = a1;
        // stage B transposed: Btw[n][bk2] = B[k0+2bk2][n] | B[k0+2bk2+1][n]<<16
        const unsigned short* gb0 = B + (size_t)(k0 + 2 * bk2) * N + j0 + bng * 8;
        uint4 b0 = *(const uint4*)gb0;
        uint4 b1 = *(const uint4*)(gb0 + N);
        const unsigned short* e0 = (const unsigned short*)&b0;
        const unsigned short* e1 = (const unsigned short*)&b1;
#pragma unroll
        for (int jj = 0; jj < 8; jj++)
            Btw[bng * 8 + jj][bk2] = (unsigned)e0[jj] | ((unsigned)e1[jj] << 16);
        __syncthreads();

        f16x8 af[4], bf[4];
#pragma unroll
        for (int ti = 0; ti < 4; ti++)
            af[ti] = *(const f16x8*)&Asd[wrow + ti * 16 + l15][q * 8];
#pragma unroll
        for (int tj = 0; tj < 4; tj++)
            bf[tj] = *(const f16x8*)&Btw[wcol + tj * 16 + l15][q * 4];
#pragma unroll
        for (int ti = 0; ti < 4; ti++)
#pragma unroll
            for (int tj = 0; tj < 4; tj++)
                acc[ti][tj] = __builtin_amdgcn_mfma_f32_16x16x32_f16(
                    af[ti], bf[tj], acc[ti][tj], 0, 0, 0);
        __syncthreads();
    }

#pragma unroll
    for (int ti = 0; ti < 4; ti++)
#pragma unroll
        for (int tj = 0; tj < 4; tj++)
#pragma unroll
            for (int reg = 0; reg < 4; reg++) {
                int row = i0 + wrow + ti * 16 + q * 4 + reg;
                int col = j0 + wcol + tj * 16 + l15;
                Pm[(size_t)row * N + col] =
                    __half_as_ushort(__float2half_rn(acc[ti][tj][reg]));
            }
}

// ---------- row sums of fp16 P -> rowc2 = 1/sum (exact stochasticity) ----------
__global__ __launch_bounds__(256) void rowsum_kernel(const unsigned short* __restrict__ P,
                                                     float* __restrict__ rowc2) {
    int b = blockIdx.x;                        // pair*4096 + row
    const unsigned short* row = P + (size_t)b * N;
    int tid = threadIdx.x;
    const uint4* rp = (const uint4*)row + tid * 2;
    uint4 w0 = rp[0], w1 = rp[1];
    const __half* h0 = (const __half*)&w0;
    const __half* h1 = (const __half*)&w1;
    float s = 0.0f;
#pragma unroll
    for (int j = 0; j < 8; j++) s += __half2float(h0[j]) + __half2float(h1[j]);
#pragma unroll
    for (int o = 32; o > 0; o >>= 1) s += __shfl_xor(s, o);
    __shared__ float red[4];
    if ((tid & 63) == 0) red[tid >> 6] = s;
    __syncthreads();
    if (tid == 0) rowc2[b] = 1.0f / (red[0] + red[1] + red[2] + red[3]);
}

// ---------- W[a][b][i][c] = rowc_a[i] * sum_j Tm_a[i][j]*Om_b[j][c] -> OW[2+2a+b] ----------
__global__ __launch_bounds__(256) void wproj_kernel(const unsigned short* __restrict__ Tm,
                                                    const float* __restrict__ rowc,
                                                    float* __restrict__ OW) {
    int b = blockIdx.x;                        // a*4096 + i
    int a = b >> 12, i = b & 4095;
    const unsigned short* row = Tm + (size_t)a * ((size_t)N * N) + (size_t)i * N;
    int tid = threadIdx.x;
    const uint4* rp = (const uint4*)row + tid * 2;
    uint4 w0 = rp[0], w1 = rp[1];
    const __half* h0 = (const __half*)&w0;
    const __half* h1 = (const __half*)&w1;
    float ta[16];
#pragma unroll
    for (int j = 0; j < 8; j++) { ta[j] = __half2float(h0[j]); ta[8 + j] = __half2float(h1[j]); }
    int j0 = tid * 16;
    float ac[2][4] = {};
#pragma unroll
    for (int j = 0; j < 16; j++) {
        float tv = ta[j];
        float4 o0 = *(const float4*)(OW + (size_t)(j0 + j) * 4);
        float4 o1 = *(const float4*)(OW + (size_t)N * 4 + (size_t)(j0 + j) * 4);
        ac[0][0] += tv * o0.x; ac[0][1] += tv * o0.y; ac[0][2] += tv * o0.z; ac[0][3] += tv * o0.w;
        ac[1][0] += tv * o1.x; ac[1][1] += tv * o1.y; ac[1][2] += tv * o1.z; ac[1][3] += tv * o1.w;
    }
#pragma unroll
    for (int e = 0; e < 8; e++) {
        float* p = &ac[e >> 2][e & 3];
#pragma unroll
        for (int o = 32; o > 0; o >>= 1) *p += __shfl_xor(*p, o);
    }
    __shared__ float red[4][8];
    if ((tid & 63) == 0)
#pragma unroll
        for (int e = 0; e < 8; e++) red[tid >> 6][e] = ac[e >> 2][e & 3];
    __syncthreads();
    if (tid < 8) {
        float t = (red[0][tid] + red[1][tid] + red[2][tid] + red[3][tid]) * rowc[(size_t)a * N + i];
        int bb = tid >> 2, c = tid & 3;
        OW[(size_t)(2 + a * 2 + bb) * (N * 4) + (size_t)i * 4 + c] = t;
    }
}

// ---------- persistent scan (R5-proven body; regular launch, p2p sync) ----------
// S steps; per step: matrix m = midx[k] (Mbase + m*N*N fp16, row-corrected by rc[m][i]);
// OPS==1: out[k] via OW[m]; OPS==2: out[2k] via OW[m>>1], out[2k+1] via OW[2+m].
__global__ __launch_bounds__(256, 2) void scan_kernel(const unsigned short* __restrict__ Mbase,
                                                      const float* __restrict__ rc,
                                                      const float* __restrict__ OW,
                                                      const unsigned char* __restrict__ midx,
                                                      float* __restrict__ vwpart,
                                                      unsigned* __restrict__ ready,
                                                      float* __restrict__ out,
                                                      int S, int OPS) {
    const int tid = threadIdx.x;
    const int jb = blockIdx.x & 15;
    const int ic = blockIdx.x >> 4;      // 0..31
    const int i0 = ic * RPB;
    const int j0 = jb * CPB;

    __shared__ float v[RPB];      // raw state rows
    __shared__ float vc[RPB];     // row-mass-corrected state rows
    __shared__ float colacc[CPB];
    __shared__ float oacc[4];
    __shared__ float oacc2[4];

    const int cg = tid & 31;             // col group: 8 cols each
    const int rg = tid >> 5;             // row group: 8 groups x 16 rows

    unsigned* wait_ctr = &ready[(ic >> 1) * 64];
    unsigned* bump_ctr = &ready[jb * 64];

    for (int k = 0; k < S; k++) {
        const int m = midx[k];
        const unsigned short* mat = Mbase + (size_t)m * ((size_t)N * N);
        const float* rcrow = rc + (size_t)m * N;
        const float* pr0 = OW + (size_t)((OPS == 2) ? (m >> 1) : m) * (N * 4);
        const float* pr1 = OW + (size_t)(2 + m) * (N * 4);
        const float* vin  = vwpart + (size_t)(k % 3) * (NPART * N);
        float*       vout = vwpart + (size_t)((k + 1) % 3) * (NPART * N);

        // ---- wait for this step's input partials (monotone counter) ----
        if (tid == 0) {
            unsigned target = 32u * (unsigned)k;
            while (AL(wait_ctr) < target) __builtin_amdgcn_s_sleep(1);
        }
        __syncthreads();

        // ---- stage v rows: sum the 32 partials for this block's 128 rows ----
        if (tid < RPB) {
            float accv = 0.0f;
#pragma unroll
            for (int p = 0; p < NPART; p++) accv += AL(&vin[p * N + i0 + tid]);
            v[tid] = accv;
            vc[tid] = accv * rcrow[i0 + tid];
        }
        colacc[tid] = 0.0f;
        if (tid < 4) { oacc[tid] = 0.0f; oacc2[tid] = 0.0f; }
        __syncthreads();

        // ---- partial matvec: rows [i0+rg*16,+16), cols [j0+cg*8,+8) ----
        const unsigned short* base = mat + (size_t)(i0 + rg * 16) * N + (j0 + cg * 8);
        float a[8];
#pragma unroll
        for (int e = 0; e < 8; e++) a[e] = 0.0f;
#pragma unroll
        for (int r = 0; r < 16; r++) {
            uint4 w = *(const uint4*)(base + (size_t)r * N);
            float vi = vc[rg * 16 + r];
            float2 f0 = __half22float2(*(__half2*)&w.x);
            float2 f1 = __half22float2(*(__half2*)&w.y);
            float2 f2 = __half22float2(*(__half2*)&w.z);
            float2 f3 = __half22float2(*(__half2*)&w.w);
            a[0] += vi * f0.x; a[1] += vi * f0.y;
            a[2] += vi * f1.x; a[3] += vi * f1.y;
            a[4] += vi * f2.x; a[5] += vi * f2.y;
            a[6] += vi * f3.x; a[7] += vi * f3.y;
        }
#pragma unroll
        for (int e = 0; e < 8; e++) atomicAdd(&colacc[cg * 8 + e], a[e]);

        // ---- fused output projections (jb==0 blocks) — RAW state v ----
        if (jb == 0) {
            int r = tid >> 2, c = tid & 3;   // r in [0,64)
            float p0 = v[r] * pr0[(size_t)(i0 + r) * 4 + c]
                     + v[r + 64] * pr0[(size_t)(i0 + r + 64) * 4 + c];
            p0 += __shfl_down(p0, 32); p0 += __shfl_down(p0, 16);
            p0 += __shfl_down(p0, 8);  p0 += __shfl_down(p0, 4);
            if ((tid & 63) < 4) atomicAdd(&oacc[c], p0);
            if (OPS == 2) {
                float p1 = v[r] * pr1[(size_t)(i0 + r) * 4 + c]
                         + v[r + 64] * pr1[(size_t)(i0 + r + 64) * 4 + c];
                p1 += __shfl_down(p1, 32); p1 += __shfl_down(p1, 16);
                p1 += __shfl_down(p1, 8);  p1 += __shfl_down(p1, 4);
                if ((tid & 63) < 4) atomicAdd(&oacc2[c], p1);
            }
        }
        __syncthreads();

        // ---- publish this block's exclusive partial slice (agent-scope) ----
        AS(&vout[(size_t)ic * N + j0 + tid], colacc[tid]);
        if (jb == 0 && tid < 4) {
            atomicAdd(&out[k * OPS * 4 + tid], oacc[tid]);
            if (OPS == 2) atomicAdd(&out[k * OPS * 4 + 4 + tid], oacc2[tid]);
        }
        __syncthreads();   // drains vmcnt(0) -> slice visible at MALL

        if (tid == 0) {
            __hip_atomic_fetch_add(bump_ctr, 1u, __ATOMIC_RELAXED,
                                   __HIP_MEMORY_SCOPE_AGENT);
        }
    }
}

extern "C" void kernel_launch(void* const* d_in, const int* in_sizes, int n_in,
                              void* d_out, int out_size, void* d_ws, size_t ws_size,
                              hipStream_t stream) {
    const float* sd  = (const float*)d_in[0];   // [4096]
    const int*   seq = (const int*)d_in[1];     // [4096]
    const float* T   = (const float*)d_in[2];   // [4096,2,4096]
    const float* O   = (const float*)d_in[3];   // [4096,2,4]
    float* out = (float*)d_out;                 // [4096,4]

    const size_t TM_SZ = (size_t)2 * N * N * 2;          // 64 MiB
    const size_t P_SZ  = (size_t)4 * N * N * 2;          // 128 MiB
    const size_t AUX_SZ = 0x202000;                       // rowc..midx block

    int pairmode = (ws_size >= TM_SZ + P_SZ + AUX_SZ);

    char* ws = (char*)d_ws;
    unsigned short* Tm = (unsigned short*)ws;
    unsigned short* P  = (unsigned short*)(ws + TM_SZ);
    char* aux = ws + (pairmode ? (TM_SZ + P_SZ) : TM_SZ);
    float* rowc   = (float*)(aux);              // 32 KB
    float* rowc2  = (float*)(aux + 0x8000);     // 64 KB
    float* OW     = (float*)(aux + 0x20000);    // 384 KB: [0..1]=Om, [2..5]=W
    float* vwpart = (float*)(aux + 0x80000);    // 1.5 MiB
    unsigned* ready = (unsigned*)(aux + 0x200000);
    unsigned char* midx = (unsigned char*)(aux + 0x201000);

    hipLaunchKernelGGL(init_kernel, dim3(1536), dim3(256), 0, stream, sd, vwpart, ready, out);
    hipLaunchKernelGGL(build_desc_kernel, dim3(1), dim3(256), 0, stream, seq, midx, pairmode);
    hipLaunchKernelGGL(softmax_T_kernel, dim3(2 * N), dim3(256), 0, stream, T, Tm, rowc);
    hipLaunchKernelGGL(softmax_O_kernel, dim3(32), dim3(256), 0, stream, O, OW);

    if (pairmode) {
        hipLaunchKernelGGL(pair_gemm_kernel, dim3(4096), dim3(256), 0, stream, Tm, P);
        hipLaunchKernelGGL(rowsum_kernel, dim3(4 * N), dim3(256), 0, stream, P, rowc2);
        hipLaunchKernelGGL(wproj_kernel, dim3(2 * N), dim3(256), 0, stream, Tm, rowc, OW);
        hipLaunchKernelGGL(scan_kernel, dim3(NJB * NPART), dim3(256), 0, stream,
                           P, rowc2, OW, midx, vwpart, ready, out, L / 2, 2);
    } else {
        hipLaunchKernelGGL(scan_kernel, dim3(NJB * NPART), dim3(256), 0, stream,
                           Tm, rowc, OW, midx, vwpart, ready, out, L, 1);
    }
}

// Round 11
// 22351.520 us; speedup vs baseline: 2.1300x; 1.0610x over previous
//
#include <hip/hip_runtime.h>
#include <hip/hip_fp16.h>

#define N 4096
#define L 4096
#define NPART 16   // i-chunks (rows 256 each)
#define NJB 32     // j-blocks (cols 128 each)
#define CPB 128    // cols per block
#define RPB 256    // rows per block

#define NN ((size_t)N * (size_t)N)
#define SLOT ((size_t)N * 4)

#define AS(p, v) __hip_atomic_store((p), (v), __ATOMIC_RELAXED, __HIP_MEMORY_SCOPE_AGENT)
#define AL(p)    __hip_atomic_load((p), __ATOMIC_RELAXED, __HIP_MEMORY_SCOPE_AGENT)

typedef _Float16 f16x8 __attribute__((ext_vector_type(8)));
typedef float f32x4 __attribute__((ext_vector_type(4)));

// ---------- init: zero d_out, seed triple partial buffer, zero ready counters ----------
__global__ __launch_bounds__(256) void init_kernel(const float* __restrict__ sd,
                                                   float* __restrict__ vwpart,
                                                   unsigned* __restrict__ ready,
                                                   float* __restrict__ out) {
    int g = blockIdx.x * 256 + threadIdx.x;          // grid 1536 -> 393216 threads
    if (g < L * 4) out[g] = 0.0f;
    if (g < 3 * NPART * N) AS(&vwpart[g], (g < N) ? sd[g] : 0.0f);  // buf0 part0 = sd
    if (g < NPART * 64) AS(&ready[g], 0u);
}

// ---------- descriptor build: robust int32/int64 decode; mode 0/1/2 = direct/pair/quad ----------
__global__ __launch_bounds__(256) void build_desc_kernel(const int* __restrict__ seq32,
                                                         unsigned char* __restrict__ midx,
                                                         int mode) {
    __shared__ int any_odd;
    if (threadIdx.x == 0) any_odd = 0;
    __syncthreads();
    int acc = 0;
    for (int i = threadIdx.x; i < L / 2; i += 256) acc |= seq32[2 * i + 1];
    if (acc) any_odd = 1;
    __syncthreads();
    const int is64 = (any_odd == 0);
#define SYM(t) ((is64 ? seq32[2 * (t)] : seq32[(t)]) & 1)
    if (mode == 2) {
        for (int k = threadIdx.x; k < L / 4; k += 256)
            midx[k] = (unsigned char)(SYM(4 * k) * 8 + SYM(4 * k + 1) * 4 +
                                      SYM(4 * k + 2) * 2 + SYM(4 * k + 3));
    } else if (mode == 1) {
        for (int k = threadIdx.x; k < L / 2; k += 256)
            midx[k] = (unsigned char)(SYM(2 * k) * 2 + SYM(2 * k + 1));
    } else {
        for (int t = threadIdx.x; t < L; t += 256)
            midx[t] = (unsigned char)SYM(t);
    }
#undef SYM
}

// ---------- softmax over T rows -> fp16 Tm[s][i][j] + row-mass correction ----------
__global__ __launch_bounds__(256) void softmax_T_kernel(const float* __restrict__ T,
                                                        unsigned short* __restrict__ Tm,
                                                        float* __restrict__ rowc) {
    int row = blockIdx.x;              // 0..8191 == i*2 + s
    int i = row >> 1, s = row & 1;
    const float* src = T + (size_t)row * N;
    unsigned short* dst = Tm + ((size_t)s << 24) + ((size_t)i << 12);
    int tid = threadIdx.x;

    float vals[16];
    float mx = -1e30f;
#pragma unroll
    for (int k = 0; k < 16; k++) {
        vals[k] = src[tid + (k << 8)];
        mx = fmaxf(mx, vals[k]);
    }
#pragma unroll
    for (int o = 32; o > 0; o >>= 1) mx = fmaxf(mx, __shfl_xor(mx, o));
    __shared__ float red[4];
    int wid = tid >> 6;
    if ((tid & 63) == 0) red[wid] = mx;
    __syncthreads();
    mx = fmaxf(fmaxf(red[0], red[1]), fmaxf(red[2], red[3]));
    __syncthreads();

    float sum = 0.0f;
#pragma unroll
    for (int k = 0; k < 16; k++) {
        vals[k] = __expf(vals[k] - mx);
        sum += vals[k];
    }
#pragma unroll
    for (int o = 32; o > 0; o >>= 1) sum += __shfl_xor(sum, o);
    if ((tid & 63) == 0) red[wid] = sum;
    __syncthreads();
    sum = red[0] + red[1] + red[2] + red[3];
    __syncthreads();
    float inv = 1.0f / sum;

    float qs = 0.0f;
#pragma unroll
    for (int k = 0; k < 16; k++) {
        __half h = __float2half_rn(vals[k] * inv);
        dst[tid + (k << 8)] = __half_as_ushort(h);
        qs += __half2float(h);
    }
#pragma unroll
    for (int o = 32; o > 0; o >>= 1) qs += __shfl_xor(qs, o);
    if ((tid & 63) == 0) red[wid] = qs;
    __syncthreads();
    if (tid == 0) {
        float q = red[0] + red[1] + red[2] + red[3];
        rowc[(size_t)s * N + i] = 1.0f / q;
    }
}

// ---------- softmax over O rows (4 wide) -> fp32 OW slots 0,1 ----------
__global__ __launch_bounds__(256) void softmax_O_kernel(const float* __restrict__ O,
                                                        float* __restrict__ OW) {
    int r = blockIdx.x * 256 + threadIdx.x;        // 0..8191 == i*2 + s
    if (r < 2 * N) {
        float4 x = *(const float4*)(O + (size_t)r * 4);
        float mx = fmaxf(fmaxf(x.x, x.y), fmaxf(x.z, x.w));
        float e0 = __expf(x.x - mx), e1 = __expf(x.y - mx);
        float e2 = __expf(x.z - mx), e3 = __expf(x.w - mx);
        float inv = 1.0f / (e0 + e1 + e2 + e3);
        int i = r >> 1, s = r & 1;
        *(float4*)(OW + (size_t)s * SLOT + (size_t)i * 4) =
            make_float4(e0 * inv, e1 * inv, e2 * inv, e3 * inv);
    }
}

// ---------- MFMA GEMM: C[pair] = A[pair>>ash] x B[pair&bmask], fp16 in/out ----------
// (validated in R10) grid = npairs*1024 blocks; 128x128 C-tile; 4 waves x 64x64.
__global__ __launch_bounds__(256) void gemm_kernel(const unsigned short* __restrict__ Abase,
                                                   const unsigned short* __restrict__ Bbase,
                                                   unsigned short* __restrict__ Cbase,
                                                   int ash, int bmask) {
    int bid = blockIdx.x;
    int pair = bid >> 10;
    int tile = bid & 1023;
    int i0 = (tile >> 5) << 7;
    int j0 = (tile & 31) << 7;
    const unsigned short* A = Abase + (size_t)(pair >> ash) * NN;
    const unsigned short* B = Bbase + (size_t)(pair & bmask) * NN;
    unsigned short* Pm = Cbase + (size_t)pair * NN;

    __shared__ _Float16 Asd[128][40];
    __shared__ unsigned int Btw[128][20];

    const int tid = threadIdx.x;
    const int w = tid >> 6, ln = tid & 63;
    const int wrow = (w >> 1) << 6, wcol = (w & 1) << 6;
    const int q = ln >> 4, l15 = ln & 15;

    const int ar = tid >> 1, ah = tid & 1;
    const int bk2 = tid & 15, bng = tid >> 4;

    f32x4 acc[4][4] = {};

    for (int k0 = 0; k0 < N; k0 += 32) {
        const uint4* ga = (const uint4*)(A + (size_t)(i0 + ar) * N + k0 + ah * 16);
        uint4 a0 = ga[0], a1 = ga[1];
        *(uint4*)&Asd[ar][ah * 16] = a0;
        *(uint4*)&Asd[ar][ah * 16 + 8] = a1;
        const unsigned short* gb0 = B + (size_t)(k0 + 2 * bk2) * N + j0 + bng * 8;
        uint4 b0 = *(const uint4*)gb0;
        uint4 b1 = *(const uint4*)(gb0 + N);
        const unsigned short* e0 = (const unsigned short*)&b0;
        const unsigned short* e1 = (const unsigned short*)&b1;
#pragma unroll
        for (int jj = 0; jj < 8; jj++)
            Btw[bng * 8 + jj][bk2] = (unsigned)e0[jj] | ((unsigned)e1[jj] << 16);
        __syncthreads();

        f16x8 af[4], bf[4];
#pragma unroll
        for (int ti = 0; ti < 4; ti++)
            af[ti] = *(const f16x8*)&Asd[wrow + ti * 16 + l15][q * 8];
#pragma unroll
        for (int tj = 0; tj < 4; tj++)
            bf[tj] = *(const f16x8*)&Btw[wcol + tj * 16 + l15][q * 4];
#pragma unroll
        for (int ti = 0; ti < 4; ti++)
#pragma unroll
            for (int tj = 0; tj < 4; tj++)
                acc[ti][tj] = __builtin_amdgcn_mfma_f32_16x16x32_f16(
                    af[ti], bf[tj], acc[ti][tj], 0, 0, 0);
        __syncthreads();
    }

#pragma unroll
    for (int ti = 0; ti < 4; ti++)
#pragma unroll
        for (int tj = 0; tj < 4; tj++)
#pragma unroll
            for (int reg = 0; reg < 4; reg++) {
                int row = i0 + wrow + ti * 16 + q * 4 + reg;
                int col = j0 + wcol + tj * 16 + l15;
                Pm[(size_t)row * N + col] =
                    __half_as_ushort(__float2half_rn(acc[ti][tj][reg]));
            }
}

// ---------- row sums of fp16 matrices -> rc = 1/sum (exact stochasticity) ----------
__global__ __launch_bounds__(256) void rowsum_kernel(const unsigned short* __restrict__ P,
                                                     float* __restrict__ rc) {
    int b = blockIdx.x;                        // mat*4096 + row
    const unsigned short* row = P + (size_t)b * N;
    int tid = threadIdx.x;
    const uint4* rp = (const uint4*)row + tid * 2;
    uint4 w0 = rp[0], w1 = rp[1];
    const __half* h0 = (const __half*)&w0;
    const __half* h1 = (const __half*)&w1;
    float s = 0.0f;
#pragma unroll
    for (int j = 0; j < 8; j++) s += __half2float(h0[j]) + __half2float(h1[j]);
#pragma unroll
    for (int o = 32; o > 0; o >>= 1) s += __shfl_xor(s, o);
    __shared__ float red[4];
    if ((tid & 63) == 0) red[tid >> 6] = s;
    __syncthreads();
    if (tid == 0) rc[b] = 1.0f / (red[0] + red[1] + red[2] + red[3]);
}

// ---------- generic N x 4 projection: dst[i][c] = rc[i] * sum_j M[i][j]*Q[j][c] ----------
// phase 1: slots s<4 -> W1[ab]=corr(Tm_a)*Om_b (dst 2+s); s in 4..11 -> W2[abc]
//   = corr(P_ab)*Om_c (dst 6+q). phase 2: q<16 -> W3[abcd]=corr(P_ab)*W1[cd] (dst 14+q).
__global__ __launch_bounds__(256) void proj_kernel(const unsigned short* __restrict__ Tm,
                                                   const unsigned short* __restrict__ P,
                                                   const float* __restrict__ rowc,
                                                   const float* __restrict__ rowc2,
                                                   float* __restrict__ OW, int phase) {
    int bid = blockIdx.x;
    int s = bid >> 12, i = bid & 4095;
    const unsigned short* M; const float* rc; const float* Q; float* dst;
    if (phase == 1) {
        if (s < 4) { M = Tm + (size_t)(s >> 1) * NN; rc = rowc + (size_t)(s >> 1) * N;
                     Q = OW + (size_t)(s & 1) * SLOT; dst = OW + (size_t)(2 + s) * SLOT; }
        else { int q = s - 4; M = P + (size_t)(q >> 1) * NN; rc = rowc2 + (size_t)(q >> 1) * N;
               Q = OW + (size_t)(q & 1) * SLOT; dst = OW + (size_t)(6 + q) * SLOT; }
    } else {
        int q = s; M = P + (size_t)(q >> 2) * NN; rc = rowc2 + (size_t)(q >> 2) * N;
        Q = OW + (size_t)(2 + (q & 3)) * SLOT; dst = OW + (size_t)(14 + q) * SLOT;
    }
    const unsigned short* row = M + (size_t)i * N;
    int tid = threadIdx.x;
    const uint4* rp = (const uint4*)row + tid * 2;
    uint4 w0 = rp[0], w1 = rp[1];
    const __half* h0 = (const __half*)&w0;
    const __half* h1 = (const __half*)&w1;
    int j0 = tid * 16;
    float ac[4] = {};
#pragma unroll
    for (int j = 0; j < 8; j++) {
        float tv = __half2float(h0[j]);
        float4 o = *(const float4*)(Q + (size_t)(j0 + j) * 4);
        ac[0] += tv * o.x; ac[1] += tv * o.y; ac[2] += tv * o.z; ac[3] += tv * o.w;
        float tv1 = __half2float(h1[j]);
        float4 o1 = *(const float4*)(Q + (size_t)(j0 + 8 + j) * 4);
        ac[0] += tv1 * o1.x; ac[1] += tv1 * o1.y; ac[2] += tv1 * o1.z; ac[3] += tv1 * o1.w;
    }
#pragma unroll
    for (int e = 0; e < 4; e++)
#pragma unroll
        for (int o = 32; o > 0; o >>= 1) ac[e] += __shfl_xor(ac[e], o);
    __shared__ float red[4][4];
    if ((tid & 63) == 0)
#pragma unroll
        for (int e = 0; e < 4; e++) red[tid >> 6][e] = ac[e];
    __syncthreads();
    if (tid < 4)
        dst[(size_t)i * 4 + tid] =
            (red[0][tid] + red[1][tid] + red[2][tid] + red[3][tid]) * rc[i];
}

// ---------- persistent scan (regular launch, p2p sync; NPART=16 tiling) ----------
// 512 blocks: jb = bid&31 (128 cols), ic = bid>>5 (256 rows).
// wait ready[ic] >= 32k (32 producers: jb_p in {2ic,2ic+1} x 16 ic_p);
// bump ready[jb>>1]. Triple-buffered partials (two-level transitivity => safe).
// Block jb<OPS computes output projection jb via OW slot (m,jb)-indexed.
__global__ __launch_bounds__(256, 2) void scan_kernel(const unsigned short* __restrict__ Mbase,
                                                      const float* __restrict__ rc,
                                                      const float* __restrict__ OW,
                                                      const unsigned char* __restrict__ midx,
                                                      float* __restrict__ vwpart,
                                                      unsigned* __restrict__ ready,
                                                      float* __restrict__ out,
                                                      int S, int OPS) {
    const int tid = threadIdx.x;
    const int jb = blockIdx.x & 31;
    const int ic = blockIdx.x >> 5;      // 0..15
    const int i0 = ic * RPB;
    const int j0 = jb * CPB;

    __shared__ float v[RPB];      // raw state rows
    __shared__ float vc[RPB];     // row-mass-corrected state rows
    __shared__ float colacc[CPB];
    __shared__ float oacc[4];

    const int cg = tid & 15;             // col group: 8 cols each
    const int rg = tid >> 4;             // row group: 16 groups x 16 rows

    unsigned* wait_ctr = &ready[ic * 64];
    unsigned* bump_ctr = &ready[(jb >> 1) * 64];

    for (int k = 0; k < S; k++) {
        const int m = midx[k];
        const unsigned short* mat = Mbase + (size_t)m * NN;
        const float* rcrow = rc + (size_t)m * N;
        const float* vin  = vwpart + (size_t)(k % 3) * (NPART * N);
        float*       vout = vwpart + (size_t)((k + 1) % 3) * (NPART * N);

        // ---- wait for this step's input partials (monotone counter) ----
        if (tid == 0) {
            unsigned target = 32u * (unsigned)k;
            while (AL(wait_ctr) < target) __builtin_amdgcn_s_sleep(1);
        }
        __syncthreads();

        // ---- stage v rows: all 256 threads sum 16 partials for one row ----
        {
            float accv = 0.0f;
#pragma unroll
            for (int p = 0; p < NPART; p++) accv += AL(&vin[p * N + i0 + tid]);
            v[tid] = accv;
            vc[tid] = accv * rcrow[i0 + tid];
        }
        if (tid < CPB) colacc[tid] = 0.0f;
        if (tid < 4) oacc[tid] = 0.0f;
        __syncthreads();

        // ---- partial matvec: rows [i0+rg*16,+16), cols [j0+cg*8,+8) ----
        const unsigned short* base = mat + (size_t)(i0 + rg * 16) * N + (j0 + cg * 8);
        float a[8];
#pragma unroll
        for (int e = 0; e < 8; e++) a[e] = 0.0f;
#pragma unroll
        for (int r = 0; r < 16; r++) {
            uint4 w = *(const uint4*)(base + (size_t)r * N);
            float vi = vc[rg * 16 + r];
            float2 f0 = __half22float2(*(__half2*)&w.x);
            float2 f1 = __half22float2(*(__half2*)&w.y);
            float2 f2 = __half22float2(*(__half2*)&w.z);
            float2 f3 = __half22float2(*(__half2*)&w.w);
            a[0] += vi * f0.x; a[1] += vi * f0.y;
            a[2] += vi * f1.x; a[3] += vi * f1.y;
            a[4] += vi * f2.x; a[5] += vi * f2.y;
            a[6] += vi * f3.x; a[7] += vi * f3.y;
        }
#pragma unroll
        for (int e = 0; e < 8; e++) atomicAdd(&colacc[cg * 8 + e], a[e]);

        // ---- output projection jb (blocks jb < OPS) — RAW state v ----
        if (jb < OPS) {
            int slot;
            if (OPS == 4) slot = (jb == 0) ? (m >> 3) : (jb == 1) ? 2 + (m >> 2)
                               : (jb == 2) ? 6 + (m >> 1) : 14 + m;
            else if (OPS == 2) slot = (jb == 0) ? (m >> 1) : 2 + m;
            else slot = m;
            const float* pr = OW + (size_t)slot * SLOT;
            int r = tid >> 2, c = tid & 3;   // r in [0,64)
            float p = v[r]       * pr[(size_t)(i0 + r) * 4 + c]
                    + v[r + 64]  * pr[(size_t)(i0 + r + 64) * 4 + c]
                    + v[r + 128] * pr[(size_t)(i0 + r + 128) * 4 + c]
                    + v[r + 192] * pr[(size_t)(i0 + r + 192) * 4 + c];
            p += __shfl_down(p, 32); p += __shfl_down(p, 16);
            p += __shfl_down(p, 8);  p += __shfl_down(p, 4);
            if ((tid & 63) < 4) atomicAdd(&oacc[c], p);
        }
        __syncthreads();

        // ---- publish this block's exclusive partial slice (agent-scope) ----
        if (tid < CPB) AS(&vout[(size_t)ic * N + j0 + tid], colacc[tid]);
        if (jb < OPS && tid < 4) atomicAdd(&out[(k * OPS + jb) * 4 + tid], oacc[tid]);
        __syncthreads();   // drains vmcnt(0) -> slice visible at MALL

        if (tid == 0) {
            __hip_atomic_fetch_add(bump_ctr, 1u, __ATOMIC_RELAXED,
                                   __HIP_MEMORY_SCOPE_AGENT);
        }
    }
}

extern "C" void kernel_launch(void* const* d_in, const int* in_sizes, int n_in,
                              void* d_out, int out_size, void* d_ws, size_t ws_size,
                              hipStream_t stream) {
    const float* sd  = (const float*)d_in[0];   // [4096]
    const int*   seq = (const int*)d_in[1];     // [4096]
    const float* T   = (const float*)d_in[2];   // [4096,2,4096]
    const float* O   = (const float*)d_in[3];   // [4096,2,4]
    float* out = (float*)d_out;                 // [4096,4]

    const size_t TM_SZ = 2 * NN * 2;            // 64 MiB
    const size_t P_SZ  = 4 * NN * 2;            // 128 MiB
    const size_t P4_SZ = 16 * NN * 2;           // 512 MiB
    const size_t AUX_SZ = 0x400000;             // 4 MiB aux block

    int mode = (ws_size >= TM_SZ + P_SZ + P4_SZ + AUX_SZ) ? 2
             : (ws_size >= TM_SZ + P_SZ + AUX_SZ) ? 1 : 0;

    char* ws = (char*)d_ws;
    unsigned short* Tm = (unsigned short*)ws;
    unsigned short* P  = (unsigned short*)(ws + TM_SZ);
    unsigned short* P4 = (unsigned short*)(ws + TM_SZ + P_SZ);
    char* aux = ws + (mode == 2 ? TM_SZ + P_SZ + P4_SZ
                    : mode == 1 ? TM_SZ + P_SZ : TM_SZ);
    float* rowc   = (float*)(aux);               // 32 KB
    float* rowc2  = (float*)(aux + 0x8000);      // 64 KB
    float* rowc4  = (float*)(aux + 0x18000);     // 256 KB
    float* OW     = (float*)(aux + 0x58000);     // 32 slots x 64 KB = 2 MB
    float* vwpart = (float*)(aux + 0x258000);    // 768 KB
    unsigned* ready = (unsigned*)(aux + 0x318000);
    unsigned char* midx = (unsigned char*)(aux + 0x319000);

    hipLaunchKernelGGL(init_kernel, dim3(1536), dim3(256), 0, stream, sd, vwpart, ready, out);
    hipLaunchKernelGGL(build_desc_kernel, dim3(1), dim3(256), 0, stream, seq, midx, mode);
    hipLaunchKernelGGL(softmax_T_kernel, dim3(2 * N), dim3(256), 0, stream, T, Tm, rowc);
    hipLaunchKernelGGL(softmax_O_kernel, dim3(32), dim3(256), 0, stream, O, OW);

    if (mode == 2) {
        hipLaunchKernelGGL(gemm_kernel, dim3(4 * 1024), dim3(256), 0, stream, Tm, Tm, P, 1, 1);
        hipLaunchKernelGGL(rowsum_kernel, dim3(4 * N), dim3(256), 0, stream, P, rowc2);
        hipLaunchKernelGGL(gemm_kernel, dim3(16 * 1024), dim3(256), 0, stream, P, P, P4, 2, 3);
        hipLaunchKernelGGL(rowsum_kernel, dim3(16 * N), dim3(256), 0, stream, P4, rowc4);
        hipLaunchKernelGGL(proj_kernel, dim3(12 * N), dim3(256), 0, stream, Tm, P, rowc, rowc2, OW, 1);
        hipLaunchKernelGGL(proj_kernel, dim3(16 * N), dim3(256), 0, stream, Tm, P, rowc, rowc2, OW, 2);
        hipLaunchKernelGGL(scan_kernel, dim3(512), dim3(256), 0, stream,
                           P4, rowc4, OW, midx, vwpart, ready, out, L / 4, 4);
    } else if (mode == 1) {
        hipLaunchKernelGGL(gemm_kernel, dim3(4 * 1024), dim3(256), 0, stream, Tm, Tm, P, 1, 1);
        hipLaunchKernelGGL(rowsum_kernel, dim3(4 * N), dim3(256), 0, stream, P, rowc2);
        hipLaunchKernelGGL(proj_kernel, dim3(4 * N), dim3(256), 0, stream, Tm, P, rowc, rowc2, OW, 1);
        hipLaunchKernelGGL(scan_kernel, dim3(512), dim3(256), 0, stream,
                           P, rowc2, OW, midx, vwpart, ready, out, L / 2, 2);
    } else {
        hipLaunchKernelGGL(scan_kernel, dim3(512), dim3(256), 0, stream,
                           Tm, rowc, OW, midx, vwpart, ready, out, L, 1);
    }
}